// Round 4
// baseline (476.577 us; speedup 1.0000x reference)
//
#include <hip/hip_runtime.h>
#include <hip/hip_bf16.h>
#include <math.h>

// Problem constants (N,C,H,W) = (16,128,128,128)
#define CN      128
#define HWN     16384
#define NBATCH  16
#define PLANE   (CN * HWN)
#define TSTRIDE ((size_t)NBATCH * PLANE)   // elems per tensor in kqv buf

typedef __attribute__((ext_vector_type(8))) short  short8;   // 8 bf16 = 4 VGPR
typedef __attribute__((ext_vector_type(4))) float  float4v;  // MFMA C/D

__device__ __forceinline__ unsigned short f2b(float f) {
    __hip_bfloat16 h = __float2bfloat16(f);
    return *reinterpret_cast<unsigned short*>(&h);
}
__device__ __forceinline__ unsigned packbf(float lo, float hi) {
    return (unsigned)f2b(lo) | ((unsigned)f2b(hi) << 16);
}

// ---------------------------------------------------------------------------
// Prep: weights -> bf16 wbf[o'][c] (o' = tensor*128+o), biases -> f32.
// ---------------------------------------------------------------------------
__global__ void prep_kernel(const float* __restrict__ wk, const float* __restrict__ bk,
                            const float* __restrict__ wq, const float* __restrict__ bq,
                            const float* __restrict__ wv, const float* __restrict__ bv,
                            unsigned short* __restrict__ wbf, float* __restrict__ bias)
{
    int i = blockIdx.x * 256 + threadIdx.x;   // 0..49151
    int tensor = i >> 14, oc = i & 16383;
    const float* w = tensor == 0 ? wk : (tensor == 1 ? wq : wv);
    wbf[i] = f2b(w[oc]);
    if (i < 384) {
        const float* b = i < 128 ? bk : (i < 256 ? bq : bv);
        bias[i] = b[i & 127];
    }
}

// ---------------------------------------------------------------------------
// Phase A (MFMA, swapped operands D[hw][o]): per block, tile = 8 h x 32 w,
// processed as 2 chunks of (16 w x 8 h = 128 hw, hwlocal = wl*8+dh).
// Outputs:
//   K,Q -> blocked-transpose KT[o][h8][w][h&7]  (phase B reads 16B fragments
//          straight from global, no LDS staging)
//   V   -> natural [o][h][w]                    (GEMM2 needs w-contiguous)
// All global stores are dwordx4 via wave-private LDS repack tiles.
// ---------------------------------------------------------------------------
__global__ __launch_bounds__(256) void kqv_kernel(
    const float* __restrict__ x, const unsigned short* __restrict__ wbf,
    const float* __restrict__ bias, unsigned short* __restrict__ kqv)
{
    __shared__ unsigned Xc[128 * 68];                 // [hwlocal][c/2], 34 KiB
    __shared__ unsigned short Tk[4][16 * 136];        // wave-private repack, 34 KiB

    const int h8 = blockIdx.x >> 2, wq = blockIdx.x & 3, n = blockIdx.y;
    const int h0 = h8 * 8;
    const int t = threadIdx.x, lane = t & 63, wv = t >> 6;
    const int l15 = lane & 15, quad = lane >> 4;
    unsigned short* T = Tk[wv];

    for (int chunk = 0; chunk < 2; ++chunk) {
        const int w0 = wq * 32 + chunk * 16;
        __syncthreads();   // Xc safe to overwrite (prev chunk's readers done)

        // ---- stage x (fp32 [c][h][w]) -> LDS bf16 [wl*8+dh][c] ----
        {
            const int hwl = t & 127, half = t >> 7;
            const int wl = hwl >> 3, dh = hwl & 7;
            const float* xp = x + (size_t)n * PLANE + (size_t)(h0 + dh) * 128 + w0 + wl;
            #pragma unroll
            for (int i = 0; i < 8; ++i) {
                const int c0 = (half * 8 + i) * 8;
                float v[8];
                #pragma unroll
                for (int cc = 0; cc < 8; ++cc) v[cc] = xp[(size_t)(c0 + cc) * HWN];
                uint4 u;
                u.x = packbf(v[0], v[1]); u.y = packbf(v[2], v[3]);
                u.z = packbf(v[4], v[5]); u.w = packbf(v[6], v[7]);
                *(uint4*)&Xc[hwl * 68 + c0 / 2] = u;
            }
        }
        __syncthreads();

        // ---- hoist A-fragments (X): 8 hw m-tiles x 4 k-steps ----
        short8 afr[8][4];
        #pragma unroll
        for (int mt = 0; mt < 8; ++mt)
            #pragma unroll
            for (int k = 0; k < 4; ++k)
                afr[mt][k] = *(const short8*)&Xc[(mt * 16 + l15) * 68 + k * 16 + quad * 4];

        // ---- 6 o-tiles per wave (interleaved: each wave gets 2 K, 2 Q, 2 V) ----
        for (int nt = 0; nt < 6; ++nt) {
            const int ob = (nt * 4 + wv) * 16;        // o' base, 0..368
            short8 bfr[4];
            #pragma unroll
            for (int k = 0; k < 4; ++k)
                bfr[k] = *(const short8*)&wbf[(ob + l15) * CN + k * 32 + quad * 8];
            const float bb = bias[ob + l15];
            float4v acc[8];
            #pragma unroll
            for (int mt = 0; mt < 8; ++mt) acc[mt] = (float4v){bb, bb, bb, bb};
            #pragma unroll
            for (int mt = 0; mt < 8; ++mt)
                #pragma unroll
                for (int k = 0; k < 4; ++k)
                    acc[mt] = __builtin_amdgcn_mfma_f32_16x16x32_bf16(afr[mt][k], bfr[k], acc[mt], 0, 0, 0);

            // repack to wave-private tile T[o16][hw128] (b64 writes)
            #pragma unroll
            for (int mt = 0; mt < 8; ++mt) {
                uint2 p;
                p.x = packbf(acc[mt][0], acc[mt][1]);
                p.y = packbf(acc[mt][2], acc[mt][3]);
                *(uint2*)&T[l15 * 136 + mt * 16 + quad * 4] = p;
            }

            const int tensor = ob >> 7;
            const int oo = ob & 127;
            if (tensor < 2) {
                // blocked-transpose store: KT[o][h8][w][hl]
                const int row = lane >> 2, s = lane & 3;
                unsigned short* dst = kqv + (size_t)tensor * TSTRIDE
                                    + ((size_t)n * CN + oo + row) * HWN + h8 * 1024;
                #pragma unroll
                for (int j = 0; j < 4; ++j) {
                    uint4 u = *(const uint4*)&T[row * 136 + (s + 4 * j) * 8];
                    *(uint4*)&dst[(w0 + s + 4 * j) * 8] = u;
                }
            } else {
                // V natural store: [o][h][w] (LDS gather, w-stride 8)
                const int o = lane >> 2, g = lane & 3;
                const int wlh = g & 1, dh2 = g >> 1;
                unsigned short* dst = kqv + 2 * TSTRIDE + ((size_t)n * CN + oo + o) * HWN;
                #pragma unroll
                for (int j = 0; j < 4; ++j) {
                    const int dh = j * 2 + dh2;
                    unsigned short tmp[8];
                    #pragma unroll
                    for (int i = 0; i < 8; ++i)
                        tmp[i] = T[o * 136 + (wlh * 8 + i) * 8 + dh];
                    uint4 u;
                    u.x = (unsigned)tmp[0] | ((unsigned)tmp[1] << 16);
                    u.y = (unsigned)tmp[2] | ((unsigned)tmp[3] << 16);
                    u.z = (unsigned)tmp[4] | ((unsigned)tmp[5] << 16);
                    u.w = (unsigned)tmp[6] | ((unsigned)tmp[7] << 16);
                    *(uint4*)&dst[(size_t)(h0 + dh) * 128 + w0 + wlh * 8] = u;
                }
            }
        }
    }
}

// ---------------------------------------------------------------------------
// Phase B: per (n,o) block. GEMM1 fragments (Q,K) are DIRECT 16-B global
// loads from the blocked-transpose layout (k = h: h8 = kstep*4+quad, hl = j).
// Register softmax -> At bf16 in LDS (34 KiB, only LDS use) -> GEMM2 with V
// fragments direct from natural global layout. One __syncthreads total.
// ---------------------------------------------------------------------------
__global__ __launch_bounds__(256) void attn_kernel(
    const unsigned short* __restrict__ kqv, const float* __restrict__ x,
    const float* __restrict__ gamma, float* __restrict__ out)
{
    __shared__ unsigned short At[128 * 136];   // attn^T [v][w], 34 KiB

    const int no = blockIdx.x;
    const unsigned short* KT = kqv + (size_t)no * HWN;
    const unsigned short* QT = KT + TSTRIDE;
    const unsigned short* Vg = KT + 2 * TSTRIDE;

    const int t = threadIdx.x, lane = t & 63, wv = t >> 6;
    const int l15 = lane & 15, quad = lane >> 4;

    // ---- GEMM1: S^T[v][w] = sum_h Q[h][v] K[h][w]; wave owns v-strip of 32 ----
    const int v0 = wv * 32;
    short8 afr[2][4];
    #pragma unroll
    for (int mt = 0; mt < 2; ++mt)
        #pragma unroll
        for (int k = 0; k < 4; ++k)
            afr[mt][k] = *(const short8*)&QT[(k * 4 + quad) * 1024 + (v0 + mt * 16 + l15) * 8];

    float4v acc1[2][8];
    #pragma unroll
    for (int mt = 0; mt < 2; ++mt)
        #pragma unroll
        for (int nt = 0; nt < 8; ++nt) acc1[mt][nt] = (float4v){0.f, 0.f, 0.f, 0.f};

    #pragma unroll
    for (int nt = 0; nt < 8; ++nt) {
        short8 bfr[4];
        #pragma unroll
        for (int k = 0; k < 4; ++k)
            bfr[k] = *(const short8*)&KT[(k * 4 + quad) * 1024 + (nt * 16 + l15) * 8];
        #pragma unroll
        for (int mt = 0; mt < 2; ++mt)
            #pragma unroll
            for (int k = 0; k < 4; ++k)
                acc1[mt][nt] = __builtin_amdgcn_mfma_f32_16x16x32_bf16(afr[mt][k], bfr[k], acc1[mt][nt], 0, 0, 0);
    }

    // ---- softmax over w (rows of S^T), in registers; write At bf16 ----
    const float sc = 0.08838834764831845f;   // 1/sqrt(128)
    #pragma unroll
    for (int mt = 0; mt < 2; ++mt)
        #pragma unroll
        for (int r = 0; r < 4; ++r) {
            float m = -INFINITY;
            #pragma unroll
            for (int nt = 0; nt < 8; ++nt) {
                acc1[mt][nt][r] *= sc;
                m = fmaxf(m, acc1[mt][nt][r]);
            }
            #pragma unroll
            for (int d = 1; d < 16; d <<= 1) m = fmaxf(m, __shfl_xor(m, d, 64));
            float s = 0.f;
            #pragma unroll
            for (int nt = 0; nt < 8; ++nt) {
                const float e = __expf(acc1[mt][nt][r] - m);
                acc1[mt][nt][r] = e;
                s += e;
            }
            #pragma unroll
            for (int d = 1; d < 16; d <<= 1) s += __shfl_xor(s, d, 64);
            const float inv = 1.0f / s;
            const int v = v0 + mt * 16 + quad * 4 + r;
            #pragma unroll
            for (int nt = 0; nt < 8; ++nt)
                At[v * 136 + nt * 16 + l15] = f2b(acc1[mt][nt][r] * inv);
        }
    __syncthreads();

    // ---- GEMM2: O[h][v] = sum_w V[h][w] At[v][w]; wave owns h-strip of 32 ----
    const int h0 = wv * 32;
    short8 vfr[2][4];
    #pragma unroll
    for (int mt = 0; mt < 2; ++mt)
        #pragma unroll
        for (int k = 0; k < 4; ++k)
            vfr[mt][k] = *(const short8*)&Vg[(h0 + mt * 16 + l15) * 128 + k * 32 + quad * 8];

    float4v acc2[2][8];
    #pragma unroll
    for (int mt = 0; mt < 2; ++mt)
        #pragma unroll
        for (int nt = 0; nt < 8; ++nt) acc2[mt][nt] = (float4v){0.f, 0.f, 0.f, 0.f};

    #pragma unroll
    for (int nt = 0; nt < 8; ++nt) {
        short8 bfr[4];
        #pragma unroll
        for (int k = 0; k < 4; ++k)
            bfr[k] = *(const short8*)&At[(nt * 16 + l15) * 136 + k * 32 + quad * 8];
        #pragma unroll
        for (int mt = 0; mt < 2; ++mt)
            #pragma unroll
            for (int k = 0; k < 4; ++k)
                acc2[mt][nt] = __builtin_amdgcn_mfma_f32_16x16x32_bf16(vfr[mt][k], bfr[k], acc2[mt][nt], 0, 0, 0);
    }

    // ---- epilogue: out = gamma*O + x ----
    const float g = gamma[0];
    const float* xp = x + (size_t)no * HWN;
    float*       op = out + (size_t)no * HWN;
    #pragma unroll
    for (int mt = 0; mt < 2; ++mt)
        #pragma unroll
        for (int nt = 0; nt < 8; ++nt)
            #pragma unroll
            for (int r = 0; r < 4; ++r) {
                const int idx = (h0 + mt * 16 + quad * 4 + r) * 128 + nt * 16 + l15;
                op[idx] = fmaf(g, acc2[mt][nt][r], xp[idx]);
            }
}

// ---------------------------------------------------------------------------
extern "C" void kernel_launch(void* const* d_in, const int* in_sizes, int n_in,
                              void* d_out, int out_size, void* d_ws, size_t ws_size,
                              hipStream_t stream) {
    const float* x     = (const float*)d_in[0];
    const float* wk    = (const float*)d_in[1];
    const float* bk    = (const float*)d_in[2];
    const float* wq    = (const float*)d_in[3];
    const float* bq    = (const float*)d_in[4];
    const float* wv    = (const float*)d_in[5];
    const float* bv    = (const float*)d_in[6];
    const float* gamma = (const float*)d_in[7];
    float* out = (float*)d_out;

    // ws: wbf bf16 (96 KiB) | bias f32 @192 KiB | kqv bf16 @256 KiB (192 MiB)
    unsigned short* wbf  = (unsigned short*)d_ws;
    float*          bias = (float*)((char*)d_ws + (192 << 10));
    unsigned short* kqv  = (unsigned short*)((char*)d_ws + (256 << 10));

    prep_kernel<<<192, 256, 0, stream>>>(wk, bk, wq, bq, wv, bv, wbf, bias);
    dim3 gA(64, NBATCH);   // x: h8(16) x wq(4), y: n
    kqv_kernel<<<gA, 256, 0, stream>>>(x, wbf, bias, kqv);
    attn_kernel<<<NBATCH * CN, 256, 0, stream>>>(kqv, x, gamma, out);
}